// Round 1
// baseline (99.723 us; speedup 1.0000x reference)
//
#include <hip/hip_runtime.h>
#include <stdint.h>

// iSTFT as a single fused bf16-MFMA GEMM + overlap-add.
//   frames_windowed[m][n] = sum_k X[m][k] * Tb[k][n]
//   X[m=(b,t)][k=2f+c] = transform[b,f,t,c]   (K = 514, padded to 544)
//   Tb[2f+0][n] =  s_f*cos(2*pi*f*n/512)*win[n]/512
//   Tb[2f+1][n] = -s_f*sin(2*pi*f*n/512)*win[n]/512,  s_f = (f==0||f==256)?1:2
// Overlap-add: out[b, c*256+r] = (F[c-1][256+r] + F[c][r]) / (denorm + eps)
// denorm == 1 exactly in the interior (sqrt-hann, 50% overlap); w^2 at edges.

#define EPS_F 1.1920928955078125e-07f
#define TWO_PI_OVER_512 1.2271846303085130e-02f

typedef __bf16 bf16x8 __attribute__((ext_vector_type(8)));
typedef float f32x4 __attribute__((ext_vector_type(4)));

__device__ __forceinline__ uint16_t f2bf_bits(float x) {
  return __builtin_bit_cast(uint16_t, (__bf16)x);
}
__device__ __forceinline__ float bf2f_bits(uint16_t u) {
  return (float)__builtin_bit_cast(__bf16, u);
}

// Table: K=544 rows x N=512, bf16, packed in 16B units for ds_read_b128 frags:
//   unit u = (k>>3)*512 + n ; byte = ((u<<4) ^ ((g&3)<<5)) + (k&7)*2, g=k>>3
// XOR term = LDS bank swizzle, baked into global layout so tile copies are
// verbatim (global_load_lds requires linear dest: both-sides-or-neither).
__global__ void build_table_kernel(const float* __restrict__ win,
                                   uint8_t* __restrict__ tb) {
  const int k = blockIdx.x;   // 0..543
  const int g = k >> 3;
  for (int n = threadIdx.x; n < 512; n += blockDim.x) {
    float v = 0.0f;
    if (k < 514) {
      const int f = k >> 1;
      const float s = (f == 0 || f == 256) ? 1.0f : 2.0f;
      const int a = (f * n) & 511;                 // exact angle reduction
      const float th = (float)a * TWO_PI_OVER_512;
      const float tr = (k & 1) ? -sinf(th) : cosf(th);
      v = s * tr * win[n] * (1.0f / 512.0f);
    }
    const int off = (((g * 512 + n) << 4) ^ ((g & 3) << 5)) + ((k & 7) << 1);
    *(uint16_t*)(tb + off) = f2bf_bits(v);
  }
}

// One block: batch b, 64 consecutive frames [t0, t0+64), full N=512.
// Owns output chunks [t0+1, t0+63] (+ chunk 0 / chunk 4000 at the ends).
// Adjacent blocks overlap by 1 frame (halo) -> OLA is fully block-local.
__global__ __launch_bounds__(256, 2)
void istft_fused_kernel(const float2* __restrict__ in,   // [B*257*4000] (re,im)
                        const float* __restrict__ win,   // [512]
                        const uint8_t* __restrict__ tb,  // packed table
                        float* __restrict__ out) {
  __shared__ __align__(128) uint8_t smem[65536];
  uint8_t* sA = smem;          // A staging: 64 rows x 80B (32 k-cols + pad/swz)
  uint8_t* sB = smem + 5120;   // B staging: 32768B (one K-step of the table)
  uint8_t* sF = smem;          // epilogue frames: [col 512][row 64] pitch 128B

  const int tid  = threadIdx.x;
  const int lane = tid & 63;
  const int wave = tid >> 6;
  const int b  = blockIdx.y;
  const int ib = blockIdx.x;                // 0..63
  const int t0 = (ib == 63) ? 3936 : ib * 63;

  f32x4 acc[4][8];
#pragma unroll
  for (int mi = 0; mi < 4; ++mi)
#pragma unroll
    for (int nj = 0; nj < 8; ++nj)
      acc[mi][nj] = (f32x4){0.0f, 0.0f, 0.0f, 0.0f};

  const long inBase = (long)b * 257 * 4000;  // float2 elements

#pragma unroll 1
  for (int ks = 0; ks < 17; ++ks) {
    __syncthreads();  // previous iteration's fragment reads are done
    // ---- stage A: 64 frames x 32 k (16 f, re+im interleaved) ----
    {
      bf16x8 pack;
#pragma unroll
      for (int j = 0; j < 4; ++j) {
        const int f = ks * 16 + wave * 4 + j;
        float xr = 0.0f, xi = 0.0f;
        if (f < 257) {  // pad rows must be written as ZERO (stale LDS may be NaN)
          const float2 v = in[inBase + (long)f * 4000 + (t0 + lane)];
          xr = v.x; xi = v.y;
        }
        pack[2 * j]     = (__bf16)xr;   // k_local = 8*wave + 2*j + 0
        pack[2 * j + 1] = (__bf16)xi;   // k_local = 8*wave + 2*j + 1
      }
      *(bf16x8*)(sA + lane * 80 + ((wave ^ (lane & 3)) << 4)) = pack;
    }
    // ---- stage B: verbatim contiguous 32KB (swizzle baked into table) ----
    {
      const uint8_t* src = tb + ks * 32768 + wave * 8192 + lane * 16;
      uint8_t* dst = sB + wave * 8192;
#pragma unroll
      for (int c = 0; c < 8; ++c) {
        __builtin_amdgcn_global_load_lds(
            (const __attribute__((address_space(1))) uint32_t*)(src + c * 1024),
            (__attribute__((address_space(3))) uint32_t*)(dst + c * 1024),
            16, 0, 0);
      }
    }
    __syncthreads();  // compiler drains vmcnt/lgkmcnt before s_barrier
    // ---- fragments + MFMA (wave owns cols [wave*128, wave*128+128)) ----
    bf16x8 af[4];
#pragma unroll
    for (int mi = 0; mi < 4; ++mi) {
      const int row = mi * 16 + (lane & 15);
      af[mi] = *(const bf16x8*)(sA + row * 80 + (((lane >> 4) ^ (row & 3)) << 4));
    }
    bf16x8 bfr[8];
#pragma unroll
    for (int nj = 0; nj < 8; ++nj) {
      const int n = wave * 128 + nj * 16 + (lane & 15);
      const int g = lane >> 4;
      bfr[nj] = *(const bf16x8*)(sB + ((((g * 512 + n) << 4) ^ (g << 5))));
    }
#pragma unroll
    for (int mi = 0; mi < 4; ++mi)
#pragma unroll
      for (int nj = 0; nj < 8; ++nj)
        acc[mi][nj] = __builtin_amdgcn_mfma_f32_16x16x32_bf16(
            af[mi], bfr[nj], acc[mi][nj], 0, 0, 0);
  }

  __syncthreads();  // all LDS reads done before re-using smem as sF
  // ---- epilogue: windowed frames -> sF transposed [col][row],
  //      byte = col*128 + ((row*2) ^ ((col&31)<<2))  (bank-conflict-free) ----
#pragma unroll
  for (int mi = 0; mi < 4; ++mi)
#pragma unroll
    for (int nj = 0; nj < 8; ++nj) {
      const int col = wave * 128 + nj * 16 + (lane & 15);
      const int row = mi * 16 + ((lane >> 4) << 2);  // D: row=(lane>>4)*4+r
      const int swz = (col & 31) << 2;
      const uint32_t lo = (uint32_t)f2bf_bits(acc[mi][nj][0]) |
                          ((uint32_t)f2bf_bits(acc[mi][nj][1]) << 16);
      const uint32_t hi = (uint32_t)f2bf_bits(acc[mi][nj][2]) |
                          ((uint32_t)f2bf_bits(acc[mi][nj][3]) << 16);
      *(uint32_t*)(sF + col * 128 + (((row)*2) ^ swz))       = lo;
      *(uint32_t*)(sF + col * 128 + (((row + 2) * 2) ^ swz)) = hi;
    }
  __syncthreads();

  // ---- overlap-add + normalize; thread = sample r, loop over chunks ----
  const float invd = 1.0f / (1.0f + EPS_F);
  float* outb = out + (long)b * 1024256;
#pragma unroll 1
  for (int cl = 1; cl <= 63; ++cl) {
    const int c0 = 256 + tid;
    const float v0 = bf2f_bits(*(const uint16_t*)(
        sF + c0 * 128 + (((cl - 1) * 2) ^ ((c0 & 31) << 2))));
    const float v1 = bf2f_bits(*(const uint16_t*)(
        sF + tid * 128 + ((cl * 2) ^ ((tid & 31) << 2))));
    outb[(t0 + cl) * 256 + tid] = (v0 + v1) * invd;
  }
  if (ib == 0) {  // chunk 0: only frame 0, n = r, denorm = win[r]^2
    const float w = win[tid];
    const float v = bf2f_bits(*(const uint16_t*)(
        sF + tid * 128 + (0 ^ ((tid & 31) << 2))));
    outb[tid] = v / (w * w + EPS_F);
  }
  if (ib == 63) {  // chunk 4000: only frame 3999, n = 256+r
    const int c0 = 256 + tid;
    const float w = win[c0];
    const float v = bf2f_bits(*(const uint16_t*)(
        sF + c0 * 128 + ((63 * 2) ^ ((c0 & 31) << 2))));
    outb[1024000 + tid] = v / (w * w + EPS_F);
  }
}

extern "C" void kernel_launch(void* const* d_in, const int* in_sizes, int n_in,
                              void* d_out, int out_size, void* d_ws, size_t ws_size,
                              hipStream_t stream) {
  (void)in_sizes; (void)n_in; (void)out_size; (void)ws_size;
  const float2* tr = (const float2*)d_in[0];
  const float* win = (const float*)d_in[1];
  uint8_t* tb = (uint8_t*)d_ws;  // 544*512*2 = 557056 bytes
  build_table_kernel<<<dim3(544), dim3(256), 0, stream>>>(win, tb);
  istft_fused_kernel<<<dim3(64, 16), dim3(256), 0, stream>>>(tr, win, tb,
                                                             (float*)d_out);
}

// Round 2
// 82.607 us; speedup vs baseline: 1.2072x; 1.2072x over previous
//
#include <hip/hip_runtime.h>
#include <stdint.h>

// iSTFT as a single fused bf16-MFMA GEMM + overlap-add.
//   frames_windowed[m][n] = sum_k X[m][k] * Tb[k][n]
//   X[m=(b,t)][k=2f+c] = transform[b,f,t,c]   (K = 514, padded to 544)
//   Tb[2f+0][n] =  s_f*cos(2*pi*f*n/512)*win[n]/512
//   Tb[2f+1][n] = -s_f*sin(2*pi*f*n/512)*win[n]/512,  s_f = (f==0||f==256)?1:2
// Overlap-add: out[b, c*256+r] = (F[c-1][256+r] + F[c][r]) / (denorm + eps)
// denorm == 1 exactly in the interior (sqrt-hann, 50% overlap); w^2 at edges.
//
// R2: occupancy restructure. 512-thr blocks (8 waves, wave tile M32xN128,
// acc[2][8]=64 regs), epilogue OLA buffer halved to 32 frames/pass (1 reg
// carries the straddling chunk), LDS 37888B, launch_bounds(512,4) ->
// 2 blocks/CU, 16 waves/CU (50%). Bank-conflict-free swizzles on A staging
// (old one was 8-way on lanes l,l+8) and on the 72B-pitch epilogue buffer.

#define EPS_F 1.1920928955078125e-07f
#define TWO_PI_OVER_512 1.2271846303085130e-02f

typedef __bf16 bf16x4 __attribute__((ext_vector_type(4)));
typedef __bf16 bf16x8 __attribute__((ext_vector_type(8)));
typedef float f32x4 __attribute__((ext_vector_type(4)));

__device__ __forceinline__ uint16_t f2bf_bits(float x) {
  return __builtin_bit_cast(uint16_t, (__bf16)x);
}
__device__ __forceinline__ float bf2f_bits(uint16_t u) {
  return (float)__builtin_bit_cast(__bf16, u);
}

// Table: K=544 rows x N=512, bf16, packed in 16B units for ds_read_b128 frags:
//   unit u = (k>>3)*512 + n ; byte = ((u<<4) ^ ((g&3)<<5)) + (k&7)*2, g=k>>3
// XOR term = LDS bank swizzle, baked into global layout so tile copies are
// verbatim (global_load_lds requires linear dest: both-sides-or-neither).
__global__ void build_table_kernel(const float* __restrict__ win,
                                   uint8_t* __restrict__ tb) {
  const int k = blockIdx.x;   // 0..543
  const int g = k >> 3;
  for (int n = threadIdx.x; n < 512; n += blockDim.x) {
    float v = 0.0f;
    if (k < 514) {
      const int f = k >> 1;
      const float s = (f == 0 || f == 256) ? 1.0f : 2.0f;
      const int a = (f * n) & 511;                 // exact angle reduction
      const float th = (float)a * TWO_PI_OVER_512;
      const float tr = (k & 1) ? -sinf(th) : cosf(th);
      v = s * tr * win[n] * (1.0f / 512.0f);
    }
    const int off = (((g * 512 + n) << 4) ^ ((g & 3) << 5)) + ((k & 7) << 1);
    *(uint16_t*)(tb + off) = f2bf_bits(v);
  }
}

// epilogue frame buffer: 512 cols x 32 rows bf16, pitch 72B, swizzled
__device__ __forceinline__ float rd_sf(const uint8_t* sF, int col, int row2) {
  return bf2f_bits(*(const uint16_t*)(
      sF + col * 72 + ((row2 * 2) ^ (((col >> 4) & 3) << 2))));
}

// One block: batch b, 64 consecutive frames [t0, t0+64), full N=512.
// Owns output chunks [t0+1, t0+63] (+ chunk 0 / chunk 4000 at the ends).
// Adjacent blocks overlap by 1 frame (halo) -> OLA is fully block-local.
__global__ __launch_bounds__(512, 4)
void istft_fused_kernel(const float2* __restrict__ in,   // [B*257*4000] (re,im)
                        const float* __restrict__ win,   // [512]
                        const uint8_t* __restrict__ tb,  // packed table
                        float* __restrict__ out) {
  __shared__ __align__(128) uint8_t smem[37888];
  uint8_t* sA = smem;          // A staging: 64 rows x 80B (32 k + swz region)
  uint8_t* sB = smem + 5120;   // B staging: 32768B (one K-step of the table)
  uint8_t* sF = smem;          // epilogue: 512 cols x 32 rows, pitch 72B

  const int tid  = threadIdx.x;
  const int lane = tid & 63;
  const int wave = tid >> 6;       // 0..7
  const int wn   = wave & 3;       // N-quarter
  const int wm   = wave >> 2;      // M-half
  const int colbase = wn * 128;
  const int b  = blockIdx.y;
  const int ib = blockIdx.x;                // 0..63
  const int t0 = (ib == 63) ? 3936 : ib * 63;

  f32x4 acc[2][8];
#pragma unroll
  for (int mi = 0; mi < 2; ++mi)
#pragma unroll
    for (int nj = 0; nj < 8; ++nj)
      acc[mi][nj] = (f32x4){0.0f, 0.0f, 0.0f, 0.0f};

  const long inBase = (long)b * 257 * 4000;  // float2 elements

#pragma unroll 1
  for (int ks = 0; ks < 17; ++ks) {
    __syncthreads();  // previous iteration's fragment reads are done
    // ---- stage A: 64 frames x 32 k (16 f, re+im interleaved) ----
    {
      bf16x4 pack;
#pragma unroll
      for (int j = 0; j < 2; ++j) {
        const int f = ks * 16 + wave * 2 + j;
        float xr = 0.0f, xi = 0.0f;
        if (f < 257) {  // pad rows written as ZERO (stale LDS would be junk)
          const float2 v = in[inBase + (long)f * 4000 + (t0 + lane)];
          xr = v.x; xi = v.y;
        }
        pack[2 * j]     = (__bf16)xr;   // k_local = wave*4 + 2*j + 0
        pack[2 * j + 1] = (__bf16)xi;   // k_local = wave*4 + 2*j + 1
      }
      const int fa = (lane & 3) ^ (((lane >> 3) & 1) << 1);
      *(bf16x4*)(sA + lane * 80 +
                 ((((wave >> 1) ^ fa) << 4) | ((wave & 1) << 3))) = pack;
    }
    // ---- stage B: verbatim contiguous 32KB (swizzle baked into table) ----
    {
      const uint8_t* src = tb + ks * 32768 + wave * 4096 + lane * 16;
      uint8_t* dst = sB + wave * 4096;
#pragma unroll
      for (int c = 0; c < 4; ++c) {
        __builtin_amdgcn_global_load_lds(
            (const __attribute__((address_space(1))) uint32_t*)(src + c * 1024),
            (__attribute__((address_space(3))) uint32_t*)(dst + c * 1024),
            16, 0, 0);
      }
    }
    __syncthreads();  // compiler drains vmcnt/lgkmcnt before s_barrier
    // ---- fragments + MFMA (wave: rows wm*32+[0,32), cols wn*128+[0,128)) ----
    bf16x8 af[2];
#pragma unroll
    for (int mi = 0; mi < 2; ++mi) {
      const int row = wm * 32 + mi * 16 + (lane & 15);
      const int fa = (row & 3) ^ (((row >> 3) & 1) << 1);
      af[mi] = *(const bf16x8*)(sA + row * 80 + (((lane >> 4) ^ fa) << 4));
    }
#pragma unroll
    for (int nj = 0; nj < 8; ++nj) {
      const int n = colbase + nj * 16 + (lane & 15);
      const int g = lane >> 4;
      const bf16x8 bfr = *(const bf16x8*)(sB + ((((g * 512 + n) << 4) ^ (g << 5))));
      acc[0][nj] = __builtin_amdgcn_mfma_f32_16x16x32_bf16(af[0], bfr, acc[0][nj], 0, 0, 0);
      acc[1][nj] = __builtin_amdgcn_mfma_f32_16x16x32_bf16(af[1], bfr, acc[1][nj], 0, 0, 0);
    }
  }

  // ---- epilogue: two 32-frame passes through a 36KB swizzled buffer ----
  __syncthreads();  // all GEMM LDS reads done before re-using smem as sF
  float* outb = out + (long)b * 1024256;
  const float invd = 1.0f / (1.0f + EPS_F);

  // stage group 0 (frames 0..31 = waves wm==0)
  if (wm == 0) {
#pragma unroll
    for (int mi = 0; mi < 2; ++mi)
#pragma unroll
      for (int nj = 0; nj < 8; ++nj) {
        const int col = colbase + nj * 16 + (lane & 15);
        const int q4 = mi * 16 + ((lane >> 4) << 2);  // D row=(lane>>4)*4+r
        const int swz = ((col >> 4) & 3) << 2;
        const uint32_t lo = (uint32_t)f2bf_bits(acc[mi][nj][0]) |
                            ((uint32_t)f2bf_bits(acc[mi][nj][1]) << 16);
        const uint32_t hi = (uint32_t)f2bf_bits(acc[mi][nj][2]) |
                            ((uint32_t)f2bf_bits(acc[mi][nj][3]) << 16);
        *(uint32_t*)(sF + col * 72 + ((q4 * 2) ^ swz))       = lo;
        *(uint32_t*)(sF + col * 72 + (((q4 + 2) * 2) ^ swz)) = hi;
      }
  }
  __syncthreads();
  // OLA chunks 1..31 (frames cl-1, cl both in group 0)
#pragma unroll 1
  for (int i = tid; i < 31 * 256; i += 512) {
    const int cl = 1 + (i >> 8);
    const int r  = i & 255;
    const float v0 = rd_sf(sF, 256 + r, cl - 1);
    const float v1 = rd_sf(sF, r, cl);
    outb[(t0 + cl) * 256 + r] = (v0 + v1) * invd;
  }
  if (ib == 0 && tid < 256) {  // chunk 0: only frame 0, n=r, denorm=win[r]^2
    const float w = win[tid];
    outb[tid] = rd_sf(sF, tid, 0) / (w * w + EPS_F);
  }
  // carry frame 31's upper half for the straddling chunk 32
  const float vsave = (tid < 256) ? rd_sf(sF, 256 + tid, 31) : 0.0f;
  __syncthreads();
  // stage group 1 (frames 32..63 = waves wm==1)
  if (wm == 1) {
#pragma unroll
    for (int mi = 0; mi < 2; ++mi)
#pragma unroll
      for (int nj = 0; nj < 8; ++nj) {
        const int col = colbase + nj * 16 + (lane & 15);
        const int q4 = mi * 16 + ((lane >> 4) << 2);
        const int swz = ((col >> 4) & 3) << 2;
        const uint32_t lo = (uint32_t)f2bf_bits(acc[mi][nj][0]) |
                            ((uint32_t)f2bf_bits(acc[mi][nj][1]) << 16);
        const uint32_t hi = (uint32_t)f2bf_bits(acc[mi][nj][2]) |
                            ((uint32_t)f2bf_bits(acc[mi][nj][3]) << 16);
        *(uint32_t*)(sF + col * 72 + ((q4 * 2) ^ swz))       = lo;
        *(uint32_t*)(sF + col * 72 + (((q4 + 2) * 2) ^ swz)) = hi;
      }
  }
  __syncthreads();
  if (tid < 256)  // chunk 32: frame 31 (saved) + frame 32 (row2=0)
    outb[(t0 + 32) * 256 + tid] = (vsave + rd_sf(sF, tid, 0)) * invd;
  // OLA chunks 33..63 (frames cl-1, cl in group 1; row2 = frame - 32)
#pragma unroll 1
  for (int i = tid; i < 31 * 256; i += 512) {
    const int cl = 33 + (i >> 8);
    const int r  = i & 255;
    const float v0 = rd_sf(sF, 256 + r, cl - 33);
    const float v1 = rd_sf(sF, r, cl - 32);
    outb[(t0 + cl) * 256 + r] = (v0 + v1) * invd;
  }
  if (ib == 63 && tid < 256) {  // chunk 4000: only frame 3999, n=256+r
    const float w = win[256 + tid];
    outb[1024000 + tid] = rd_sf(sF, 256 + tid, 31) / (w * w + EPS_F);
  }
}

extern "C" void kernel_launch(void* const* d_in, const int* in_sizes, int n_in,
                              void* d_out, int out_size, void* d_ws, size_t ws_size,
                              hipStream_t stream) {
  (void)in_sizes; (void)n_in; (void)out_size; (void)ws_size;
  const float2* tr = (const float2*)d_in[0];
  const float* win = (const float*)d_in[1];
  uint8_t* tb = (uint8_t*)d_ws;  // 544*512*2 = 557056 bytes
  build_table_kernel<<<dim3(544), dim3(256), 0, stream>>>(win, tb);
  istft_fused_kernel<<<dim3(64, 16), dim3(512), 0, stream>>>(tr, win, tb,
                                                             (float*)d_out);
}

// Round 3
// 77.658 us; speedup vs baseline: 1.2841x; 1.0637x over previous
//
#include <hip/hip_runtime.h>
#include <stdint.h>

// iSTFT as a single fused bf16-MFMA GEMM + overlap-add.
//   frames_windowed[m][n] = sum_k X[m][k] * Tb[k][n]
//   X[m=(b,t)][k=2f+c] = transform[b,f,t,c]   (K = 514, padded to 544)
//   Tb[2f+0][n] =  s_f*cos(2*pi*f*n/512)*win[n]/512
//   Tb[2f+1][n] = -s_f*sin(2*pi*f*n/512)*win[n]/512,  s_f = (f==0||f==256)?1:2
// Overlap-add: out[b, c*256+r] = (F[c-1][256+r] + F[c][r]) / (denorm + eps)
// denorm == 1 exactly in the interior (sqrt-hann, 50% overlap); w^2 at edges.
//
// R3: 2-phase double-buffered K-loop (T3-minimum). Stage(ks+1) — A global
// loads to regs + B global_load_lds — is issued BEFORE the ds_read+MFMA of
// step ks, so load latency hides under compute; one barrier per K-step.
// sA/sB double-buffered (75776B LDS, still 2 blocks/CU). A-write swizzle now
// includes row bit 4 (old one left lanes {l,l+16,l+32,l+48} 4-way aliased).

#define EPS_F 1.1920928955078125e-07f
#define TWO_PI_OVER_512 1.2271846303085130e-02f

typedef __bf16 bf16x4 __attribute__((ext_vector_type(4)));
typedef __bf16 bf16x8 __attribute__((ext_vector_type(8)));
typedef float f32x4 __attribute__((ext_vector_type(4)));

__device__ __forceinline__ uint16_t f2bf_bits(float x) {
  return __builtin_bit_cast(uint16_t, (__bf16)x);
}
__device__ __forceinline__ float bf2f_bits(uint16_t u) {
  return (float)__builtin_bit_cast(__bf16, u);
}
// A-tile swizzle: row*80 + ((grp ^ fa(row))<<4), fa spreads rows 8/16/32 apart
__device__ __forceinline__ int fa_swz(int row) {
  return (row & 3) ^ (((row >> 3) & 1) << 1) ^ ((row >> 4) & 3);
}

// Table: K=544 rows x N=512, bf16, packed in 16B units for ds_read_b128 frags:
//   unit u = (k>>3)*512 + n ; byte = ((u<<4) ^ ((g&3)<<5)) + (k&7)*2, g=k>>3
// XOR term = LDS bank swizzle, baked into global layout so tile copies are
// verbatim (global_load_lds requires linear dest: both-sides-or-neither).
__global__ void build_table_kernel(const float* __restrict__ win,
                                   uint8_t* __restrict__ tb) {
  const int k = blockIdx.x;   // 0..543
  const int g = k >> 3;
  for (int n = threadIdx.x; n < 512; n += blockDim.x) {
    float v = 0.0f;
    if (k < 514) {
      const int f = k >> 1;
      const float s = (f == 0 || f == 256) ? 1.0f : 2.0f;
      const int a = (f * n) & 511;                 // exact angle reduction
      const float th = (float)a * TWO_PI_OVER_512;
      const float tr = (k & 1) ? -sinf(th) : cosf(th);
      v = s * tr * win[n] * (1.0f / 512.0f);
    }
    const int off = (((g * 512 + n) << 4) ^ ((g & 3) << 5)) + ((k & 7) << 1);
    *(uint16_t*)(tb + off) = f2bf_bits(v);
  }
}

// epilogue frame buffer: 512 cols x 32 rows bf16, pitch 72B, swizzled
__device__ __forceinline__ float rd_sf(const uint8_t* sF, int col, int row2) {
  return bf2f_bits(*(const uint16_t*)(
      sF + col * 72 + ((row2 * 2) ^ (((col >> 4) & 3) << 2))));
}

// One block: batch b, 64 consecutive frames [t0, t0+64), full N=512.
// Owns output chunks [t0+1, t0+63] (+ chunk 0 / chunk 4000 at the ends).
// Adjacent blocks overlap by 1 frame (halo) -> OLA is fully block-local.
__global__ __launch_bounds__(512, 4)
void istft_fused_kernel(const float2* __restrict__ in,   // [B*257*4000] (re,im)
                        const float* __restrict__ win,   // [512]
                        const uint8_t* __restrict__ tb,  // packed table
                        float* __restrict__ out) {
  __shared__ __align__(128) uint8_t smem[75776];
  uint8_t* sA = smem;           // A staging: 2 x (64 rows x 80B)
  uint8_t* sB = smem + 10240;   // B staging: 2 x 32768B
  uint8_t* sF = smem;           // epilogue: 512 cols x 32 rows, pitch 72B

  const int tid  = threadIdx.x;
  const int lane = tid & 63;
  const int wave = tid >> 6;       // 0..7
  const int wn   = wave & 3;       // N-quarter
  const int wm   = wave >> 2;      // M-half
  const int colbase = wn * 128;
  const int b  = blockIdx.y;
  const int ib = blockIdx.x;                // 0..63
  const int t0 = (ib == 63) ? 3936 : ib * 63;

  f32x4 acc[2][8];
#pragma unroll
  for (int mi = 0; mi < 2; ++mi)
#pragma unroll
    for (int nj = 0; nj < 8; ++nj)
      acc[mi][nj] = (f32x4){0.0f, 0.0f, 0.0f, 0.0f};

  const long inBase = (long)b * 257 * 4000;  // float2 elements
  const int awz = ((((wave >> 1) ^ fa_swz(lane)) << 4) | ((wave & 1) << 3));

  // ---- prologue: stage ks=0 into buffer 0 ----
  {
    const int f0 = wave * 2;
    float2 x0 = {0.f, 0.f}, x1 = {0.f, 0.f};
    if (f0 < 257)     x0 = in[inBase + (long)f0 * 4000 + (t0 + lane)];
    if (f0 + 1 < 257) x1 = in[inBase + (long)(f0 + 1) * 4000 + (t0 + lane)];
    const uint8_t* src = tb + wave * 4096 + lane * 16;
    uint8_t* dst = sB + wave * 4096;
#pragma unroll
    for (int c = 0; c < 4; ++c)
      __builtin_amdgcn_global_load_lds(
          (const __attribute__((address_space(1))) uint32_t*)(src + c * 1024),
          (__attribute__((address_space(3))) uint32_t*)(dst + c * 1024),
          16, 0, 0);
    bf16x4 pack = {(__bf16)x0.x, (__bf16)x0.y, (__bf16)x1.x, (__bf16)x1.y};
    *(bf16x4*)(sA + lane * 80 + awz) = pack;
  }
  __syncthreads();

#pragma unroll 1
  for (int ks = 0; ks < 17; ++ks) {
    const int cur = ks & 1;
    const uint8_t* sAc = sA + cur * 5120;
    const uint8_t* sBc = sB + cur * 32768;
    uint8_t* sAn = sA + (cur ^ 1) * 5120;
    uint8_t* sBn = sB + (cur ^ 1) * 32768;

    // ---- issue stage for ks+1 FIRST (latency hides under compute) ----
    float2 ax0 = {0.f, 0.f}, ax1 = {0.f, 0.f};
    if (ks < 16) {
      const int f0 = (ks + 1) * 16 + wave * 2;
      if (f0 < 257)     ax0 = in[inBase + (long)f0 * 4000 + (t0 + lane)];
      if (f0 + 1 < 257) ax1 = in[inBase + (long)(f0 + 1) * 4000 + (t0 + lane)];
      const uint8_t* src = tb + (ks + 1) * 32768 + wave * 4096 + lane * 16;
      uint8_t* dst = sBn + wave * 4096;
#pragma unroll
      for (int c = 0; c < 4; ++c)
        __builtin_amdgcn_global_load_lds(
            (const __attribute__((address_space(1))) uint32_t*)(src + c * 1024),
            (__attribute__((address_space(3))) uint32_t*)(dst + c * 1024),
            16, 0, 0);
    }

    // ---- fragments + MFMA (wave: rows wm*32+[0,32), cols wn*128+[0,128)) --
    bf16x8 af[2];
#pragma unroll
    for (int mi = 0; mi < 2; ++mi) {
      const int row = wm * 32 + mi * 16 + (lane & 15);
      af[mi] = *(const bf16x8*)(sAc + row * 80 +
                                (((lane >> 4) ^ fa_swz(row)) << 4));
    }
#pragma unroll
    for (int nj = 0; nj < 8; ++nj) {
      const int n = colbase + nj * 16 + (lane & 15);
      const int g = lane >> 4;
      const bf16x8 bfr =
          *(const bf16x8*)(sBc + ((((g * 512 + n) << 4) ^ (g << 5))));
      acc[0][nj] = __builtin_amdgcn_mfma_f32_16x16x32_bf16(af[0], bfr,
                                                           acc[0][nj], 0, 0, 0);
      acc[1][nj] = __builtin_amdgcn_mfma_f32_16x16x32_bf16(af[1], bfr,
                                                           acc[1][nj], 0, 0, 0);
    }

    // ---- write next A tile (loads consumed here; after MFMA issue) ----
    if (ks < 16) {
      bf16x4 pack = {(__bf16)ax0.x, (__bf16)ax0.y, (__bf16)ax1.x, (__bf16)ax1.y};
      *(bf16x4*)(sAn + lane * 80 + awz) = pack;
    }
    __syncthreads();  // publishes buf[cur^1]; all reads of buf[cur] done
  }

  // ---- epilogue: two 32-frame passes through a 36KB swizzled buffer ----
  float* outb = out + (long)b * 1024256;
  const float invd = 1.0f / (1.0f + EPS_F);

  // stage group 0 (frames 0..31 = waves wm==0)
  if (wm == 0) {
#pragma unroll
    for (int mi = 0; mi < 2; ++mi)
#pragma unroll
      for (int nj = 0; nj < 8; ++nj) {
        const int col = colbase + nj * 16 + (lane & 15);
        const int q4 = mi * 16 + ((lane >> 4) << 2);  // D row=(lane>>4)*4+r
        const int swz = ((col >> 4) & 3) << 2;
        const uint32_t lo = (uint32_t)f2bf_bits(acc[mi][nj][0]) |
                            ((uint32_t)f2bf_bits(acc[mi][nj][1]) << 16);
        const uint32_t hi = (uint32_t)f2bf_bits(acc[mi][nj][2]) |
                            ((uint32_t)f2bf_bits(acc[mi][nj][3]) << 16);
        *(uint32_t*)(sF + col * 72 + ((q4 * 2) ^ swz))       = lo;
        *(uint32_t*)(sF + col * 72 + (((q4 + 2) * 2) ^ swz)) = hi;
      }
  }
  __syncthreads();
  // OLA chunks 1..31 (frames cl-1, cl both in group 0)
#pragma unroll 1
  for (int i = tid; i < 31 * 256; i += 512) {
    const int cl = 1 + (i >> 8);
    const int r  = i & 255;
    const float v0 = rd_sf(sF, 256 + r, cl - 1);
    const float v1 = rd_sf(sF, r, cl);
    outb[(t0 + cl) * 256 + r] = (v0 + v1) * invd;
  }
  if (ib == 0 && tid < 256) {  // chunk 0: only frame 0, n=r, denorm=win[r]^2
    const float w = win[tid];
    outb[tid] = rd_sf(sF, tid, 0) / (w * w + EPS_F);
  }
  // carry frame 31's upper half for the straddling chunk 32
  const float vsave = (tid < 256) ? rd_sf(sF, 256 + tid, 31) : 0.0f;
  __syncthreads();
  // stage group 1 (frames 32..63 = waves wm==1)
  if (wm == 1) {
#pragma unroll
    for (int mi = 0; mi < 2; ++mi)
#pragma unroll
      for (int nj = 0; nj < 8; ++nj) {
        const int col = colbase + nj * 16 + (lane & 15);
        const int q4 = mi * 16 + ((lane >> 4) << 2);
        const int swz = ((col >> 4) & 3) << 2;
        const uint32_t lo = (uint32_t)f2bf_bits(acc[mi][nj][0]) |
                            ((uint32_t)f2bf_bits(acc[mi][nj][1]) << 16);
        const uint32_t hi = (uint32_t)f2bf_bits(acc[mi][nj][2]) |
                            ((uint32_t)f2bf_bits(acc[mi][nj][3]) << 16);
        *(uint32_t*)(sF + col * 72 + ((q4 * 2) ^ swz))       = lo;
        *(uint32_t*)(sF + col * 72 + (((q4 + 2) * 2) ^ swz)) = hi;
      }
  }
  __syncthreads();
  if (tid < 256)  // chunk 32: frame 31 (saved) + frame 32 (row2=0)
    outb[(t0 + 32) * 256 + tid] = (vsave + rd_sf(sF, tid, 0)) * invd;
  // OLA chunks 33..63 (frames cl-1, cl in group 1; row2 = frame - 32)
#pragma unroll 1
  for (int i = tid; i < 31 * 256; i += 512) {
    const int cl = 33 + (i >> 8);
    const int r  = i & 255;
    const float v0 = rd_sf(sF, 256 + r, cl - 33);
    const float v1 = rd_sf(sF, r, cl - 32);
    outb[(t0 + cl) * 256 + r] = (v0 + v1) * invd;
  }
  if (ib == 63 && tid < 256) {  // chunk 4000: only frame 3999, n=256+r
    const float w = win[256 + tid];
    outb[1024000 + tid] = rd_sf(sF, 256 + tid, 31) / (w * w + EPS_F);
  }
}

extern "C" void kernel_launch(void* const* d_in, const int* in_sizes, int n_in,
                              void* d_out, int out_size, void* d_ws, size_t ws_size,
                              hipStream_t stream) {
  (void)in_sizes; (void)n_in; (void)out_size; (void)ws_size;
  const float2* tr = (const float2*)d_in[0];
  const float* win = (const float*)d_in[1];
  uint8_t* tb = (uint8_t*)d_ws;  // 544*512*2 = 557056 bytes
  build_table_kernel<<<dim3(544), dim3(256), 0, stream>>>(win, tb);
  istft_fused_kernel<<<dim3(64, 16), dim3(512), 0, stream>>>(tr, win, tb,
                                                             (float*)d_out);
}